// Round 1
// baseline (212.351 us; speedup 1.0000x reference)
//
#include <hip/hip_runtime.h>

// PairwiseAUCLoss: per class c (C=14), take the FIRST 32 positive-target
// logits and FIRST 64 negative-target logits (in row order), compute
// mean over valid pairs of softplus(-(pos - neg)), then mean over active
// classes. Targets in {-1,0,1}: -1 ignore, 0 neg, 1 pos.
//
// Strategy: 1 block, 14 waves (wave = class). Each wave scans rows 64 at a
// time with 64-bit ballot + prefix popcount to assign in-order ranks into
// LDS buffers; uniform early exit when both buffers are full (expected
// after ~3-5 iterations since P(pos)=P(neg)=1/3). Then a 32x64 pairwise
// softplus sum per wave, shuffle-reduce, and a scalar combine.

#define B_ROWS 2097152
#define C_CLS 14
#define MAX_POS 32
#define MAX_NEG 64

__device__ __forceinline__ float stable_softplus(float x) {
    // log(1 + exp(x)) = max(x,0) + log1p(exp(-|x|))
    return fmaxf(x, 0.0f) + log1pf(expf(-fabsf(x)));
}

__global__ __launch_bounds__(896) void pairwise_auc_kernel(
        const float* __restrict__ logits,
        const int* __restrict__ targets,
        float* __restrict__ out) {
    __shared__ float posBuf[C_CLS][MAX_POS];
    __shared__ float negBuf[C_CLS][MAX_NEG];
    __shared__ float lossS[C_CLS];
    __shared__ int activeS[C_CLS];

    const int tid = threadIdx.x;
    const int wave = tid >> 6;      // 0..13 -> class index
    const int lane = tid & 63;
    const int c = wave;

    int cntPos = 0;   // wave-uniform (derived from ballots)
    int cntNeg = 0;

    const unsigned long long lmask = (1ull << lane) - 1ull;  // lanes below me

    for (long long base = 0; base < B_ROWS; base += 64) {
        const long long row = base + (long long)lane;
        const int t = targets[row * C_CLS + c];
        const bool isPos = (t == 1);
        const bool isNeg = (t == 0);
        const unsigned long long pm = __ballot(isPos);
        const unsigned long long nm = __ballot(isNeg);

        if (isPos | isNeg) {
            const float v = logits[row * C_CLS + c];
            if (isPos) {
                const int r = cntPos + (int)__popcll(pm & lmask);
                if (r < MAX_POS) posBuf[c][r] = v;
            } else {
                const int r = cntNeg + (int)__popcll(nm & lmask);
                if (r < MAX_NEG) negBuf[c][r] = v;
            }
        }
        cntPos = min(cntPos + (int)__popcll(pm), MAX_POS);  // == min(total, 32)
        cntNeg = min(cntNeg + (int)__popcll(nm), MAX_NEG);  // == min(total, 64)
        if (cntPos >= MAX_POS && cntNeg >= MAX_NEG) break;  // wave-uniform
    }

    // Cross-lane LDS visibility within each wave (and cheap, single block).
    __syncthreads();

    // Pairwise sum: lane j owns negBuf[c][j], loop over valid positives.
    float s = 0.0f;
    if (lane < cntNeg) {
        const float nv = negBuf[c][lane];
        for (int i = 0; i < cntPos; ++i) {
            const float d = posBuf[c][i] - nv;   // margin = 0
            s += stable_softplus(-d);
        }
    }
    // wave64 reduction
    #pragma unroll
    for (int off = 32; off > 0; off >>= 1)
        s += __shfl_down(s, off, 64);

    if (lane == 0) {
        const bool active = (cntPos > 0) && (cntNeg > 0);
        const float pairs = (float)cntPos * (float)cntNeg;
        lossS[c] = active ? (s / fmaxf(pairs, 1.0f)) : 0.0f;
        activeS[c] = active ? 1 : 0;
    }
    __syncthreads();

    if (tid == 0) {
        float tot = 0.0f;
        int cnt = 0;
        #pragma unroll
        for (int i = 0; i < C_CLS; ++i) {
            tot += lossS[i];
            cnt += activeS[i];
        }
        out[0] = (cnt > 0) ? (tot / (float)cnt) : 0.0f;
    }
}

extern "C" void kernel_launch(void* const* d_in, const int* in_sizes, int n_in,
                              void* d_out, int out_size, void* d_ws, size_t ws_size,
                              hipStream_t stream) {
    const float* logits = (const float*)d_in[0];
    const int* targets = (const int*)d_in[1];
    float* out = (float*)d_out;
    (void)in_sizes; (void)n_in; (void)out_size; (void)d_ws; (void)ws_size;

    pairwise_auc_kernel<<<1, 896, 0, stream>>>(logits, targets, out);
}